// Round 2
// baseline (13.117 us; speedup 1.0000x reference)
//
#include <hip/hip_runtime.h>

// out[b,n,k] = |scale| * sum_d (table[d,k] - x[b,n,d])^2
//            = |scale| * ( T2[k] + X2[row] - 2 * dot(x_row, t_k) )
// B=4, N=2048, D=64, K=256, fp32.
//
// Block = 64 threads (1 wave), TD_R=4 rows per block. Each thread owns 4
// consecutive k (float4 table loads, 1KB/wave coalesced). x staged in LDS
// (1 KB) and read as broadcast ds_read_b128 (16B, conflict-free). X2 via
// wave-parallel shfl reduction. float4 stores. Grid 2048 -> 2 waves/SIMD.

#define TD_D 64
#define TD_K 256
#define TD_R 4

typedef float f4 __attribute__((ext_vector_type(4)));

__global__ void TableDistance_5669356831001_kernel(
    const float* __restrict__ x,      // [8192, 64]
    const float* __restrict__ table,  // [64, 256]
    const float* __restrict__ scale,  // [1]
    float* __restrict__ out)          // [8192, 256]
{
    const int lane = threadIdx.x;            // 0..63
    const int row0 = blockIdx.x * TD_R;

    __shared__ f4 xs[TD_R][TD_D / 4];        // 4 rows x 64 floats = 1 KB

    // Stage x: lane l -> row (l>>4), d-chunk (l&15). One float4 per lane,
    // coalesced 1KB wave read.
    const int sr = lane >> 4, sc = lane & 15;
    f4 xv = *(const f4*)&x[(size_t)(row0 + sr) * TD_D + sc * 4];
    xs[sr][sc] = xv;

    // X2 per row: square own float4, butterfly-reduce within 16-lane groups.
    float px = xv.x * xv.x + xv.y * xv.y + xv.z * xv.z + xv.w * xv.w;
    px += __shfl_xor(px, 1);
    px += __shfl_xor(px, 2);
    px += __shfl_xor(px, 4);
    px += __shfl_xor(px, 8);
    float x2[TD_R];
    #pragma unroll
    for (int r = 0; r < TD_R; ++r) x2[r] = __shfl(px, r * 16);

    __syncthreads();   // single-wave block; cheap ordering for LDS

    const f4* tb = (const f4*)table;         // [64][64] of float4 over k
    f4 acc[TD_R];
    #pragma unroll
    for (int r = 0; r < TD_R; ++r) acc[r] = (f4){0.f, 0.f, 0.f, 0.f};
    f4 t2 = {0.f, 0.f, 0.f, 0.f};

    #pragma unroll
    for (int dc = 0; dc < TD_D / 4; ++dc) {  // 16 chunks of 4 d-steps
        f4 t0 = tb[(dc * 4 + 0) * 64 + lane];
        f4 t1 = tb[(dc * 4 + 1) * 64 + lane];
        f4 t2v = tb[(dc * 4 + 2) * 64 + lane];
        f4 t3 = tb[(dc * 4 + 3) * 64 + lane];
        t2 += t0 * t0 + t1 * t1 + t2v * t2v + t3 * t3;
        #pragma unroll
        for (int r = 0; r < TD_R; ++r) {
            f4 xc = xs[r][dc];               // broadcast ds_read_b128
            acc[r] += t0 * xc.x + t1 * xc.y + t2v * xc.z + t3 * xc.w;
        }
    }

    const float s = fabsf(scale[0]);
    #pragma unroll
    for (int r = 0; r < TD_R; ++r) {
        f4 res = s * (t2 + x2[r] - 2.0f * acc[r]);
        *(f4*)&out[(size_t)(row0 + r) * TD_K + lane * 4] = res;
    }
}

extern "C" void kernel_launch(void* const* d_in, const int* in_sizes, int n_in,
                              void* d_out, int out_size, void* d_ws, size_t ws_size,
                              hipStream_t stream) {
    const float* x     = (const float*)d_in[0];   // [4,2048,64]
    const float* table = (const float*)d_in[1];   // [1,1,64,256]
    const float* scale = (const float*)d_in[2];   // [1,1,1]
    float* out = (float*)d_out;                   // [4,2048,256]

    const int nrows = 4 * 2048;                   // 8192
    const int grid  = nrows / TD_R;               // 2048 blocks of 1 wave
    TableDistance_5669356831001_kernel<<<grid, 64, 0, stream>>>(x, table, scale, out);
}